// Round 1
// baseline (504.584 us; speedup 1.0000x reference)
//
#include <hip/hip_runtime.h>

#define BB 32
#define HH 224
#define WW 224
#define CC 3
#define FF 64
#define NPIX (BB * HH * WW)          // 1,605,632
#define NBLK_MED (NPIX / 256)        // 6272 exactly
#define NOUT ((long long)NPIX * FF)  // 102,760,448

// ---------------- Kernel 1: median of 27 + per-block partial sums ----------
__global__ __launch_bounds__(256) void median_kernel(const float* __restrict__ x,
                                                     float* __restrict__ med,
                                                     float* __restrict__ partial) {
    const int idx = blockIdx.x * 256 + threadIdx.x;   // < NPIX by construction
    const int w = idx % WW;
    const int t = idx / WW;
    const int h = t % HH;
    const int b = t / HH;

    float v[27];
    #pragma unroll
    for (int i = 0; i < 3; ++i) {
        const int hh = h + i - 1;
        #pragma unroll
        for (int j = 0; j < 3; ++j) {
            const int ww = w + j - 1;
            const bool ok = (hh >= 0) && (hh < HH) && (ww >= 0) && (ww < WW);
            const float* p = x + (((long long)b * HH + hh) * WW + ww) * CC;
            #pragma unroll
            for (int c = 0; c < CC; ++c) {
                v[(i * 3 + j) * 3 + c] = ok ? p[c] : 0.0f;   // TF SAME zero pad
            }
        }
    }

    // Partial selection sort: after this, v[13] = 14th smallest = median.
    // Fully unrolled -> all indices compile-time constants -> stays in VGPRs.
    #pragma unroll
    for (int k = 0; k <= 13; ++k) {
        #pragma unroll
        for (int j = k + 1; j < 27; ++j) {
            const float lo = fminf(v[k], v[j]);
            const float hi = fmaxf(v[k], v[j]);
            v[k] = lo;
            v[j] = hi;
        }
    }
    const float m = v[13];
    med[idx] = m;

    // deterministic block-sum for the global mean
    __shared__ float sdata[256];
    sdata[threadIdx.x] = m;
    __syncthreads();
    #pragma unroll
    for (int s = 128; s > 0; s >>= 1) {
        if (threadIdx.x < s) sdata[threadIdx.x] += sdata[threadIdx.x + s];
        __syncthreads();
    }
    if (threadIdx.x == 0) partial[blockIdx.x] = sdata[0];
}

// ---------------- Kernel 2: reduce partials -> mean scalar ------------------
__global__ __launch_bounds__(256) void mean_kernel(const float* __restrict__ partial,
                                                   float* __restrict__ mean_out) {
    float s = 0.0f;
    for (int i = threadIdx.x; i < NBLK_MED; i += 256) s += partial[i];
    __shared__ float sdata[256];
    sdata[threadIdx.x] = s;
    __syncthreads();
    #pragma unroll
    for (int st = 128; st > 0; st >>= 1) {
        if (threadIdx.x < st) sdata[threadIdx.x] += sdata[threadIdx.x + st];
        __syncthreads();
    }
    if (threadIdx.x == 0) mean_out[0] = sdata[0] / (float)NPIX;
}

// ---------------- Kernel 3: 3x3 conv of centered median, 64 filters --------
__global__ __launch_bounds__(256) void conv_kernel(const float* __restrict__ med,
                                                   const float* __restrict__ Wt,
                                                   const float* __restrict__ mean_p,
                                                   float* __restrict__ out) {
    const long long idx = (long long)blockIdx.x * 256 + threadIdx.x;
    const int f = (int)(idx & 63);
    const long long pix = idx >> 6;           // one wave64 == one pixel
    const int w = (int)(pix % WW);
    const long long t2 = pix / WW;
    const int h = (int)(t2 % HH);
    const int b = (int)(t2 / HH);

    __shared__ float wsm[9 * FF];             // 576 floats = 2.3 KB
    for (int i = threadIdx.x; i < 9 * FF; i += 256) wsm[i] = Wt[i];
    __syncthreads();

    const float mean = mean_p[0];

    float acc = 0.0f;
    #pragma unroll
    for (int i = 0; i < 3; ++i) {
        const int hh = h + i - 1;
        #pragma unroll
        for (int j = 0; j < 3; ++j) {
            const int ww = w + j - 1;
            if (hh >= 0 && hh < HH && ww >= 0 && ww < WW) {
                // conv pads the CENTERED map with zeros -> only in-bounds
                // taps contribute (med - mean).
                const float m = med[((long long)b * HH + hh) * WW + ww] - mean;
                acc += m * wsm[(i * 3 + j) * FF + f];
            }
        }
    }
    out[idx] = acc;
}

extern "C" void kernel_launch(void* const* d_in, const int* in_sizes, int n_in,
                              void* d_out, int out_size, void* d_ws, size_t ws_size,
                              hipStream_t stream) {
    const float* x  = (const float*)d_in[0];   // [32,224,224,3]
    const float* Wt = (const float*)d_in[1];   // [3,3,1,64]
    float* out = (float*)d_out;                // [32,224,224,64]

    float* med     = (float*)d_ws;             // NPIX floats
    float* partial = med + NPIX;               // NBLK_MED floats
    float* mean_p  = partial + NBLK_MED;       // 1 float

    median_kernel<<<NBLK_MED, 256, 0, stream>>>(x, med, partial);
    mean_kernel<<<1, 256, 0, stream>>>(partial, mean_p);

    const long long nblk = NOUT / 256;         // 401,408
    conv_kernel<<<(int)nblk, 256, 0, stream>>>(med, Wt, mean_p, out);
}

// Round 2
// 144.885 us; speedup vs baseline: 3.4827x; 3.4827x over previous
//
#include <hip/hip_runtime.h>

#define BB 32
#define HH 224
#define WW 224
#define CC 3
#define FF 64
#define NPIX (BB * HH * WW)          // 1,605,632
#define NBLK_MED (NPIX / 256)        // 6272 exactly
#define NOUT ((long long)NPIX * FF)  // 102,760,448

// padded centered-median buffer: [32][226][228], zero borders
#define PH 226
#define PW 228
#define PB (PH * PW)                 // 51,528
#define NPAD (BB * PB)               // 1,648,896 (divisible by 256 -> 6441 blocks)

// ---------------- Kernel 1: median of 27 + per-block partial sums ----------
__global__ __launch_bounds__(256) void median_kernel(const float* __restrict__ x,
                                                     float* __restrict__ med,
                                                     float* __restrict__ partial) {
    const int idx = blockIdx.x * 256 + threadIdx.x;   // < NPIX by construction
    const int w = idx % WW;
    const int t = idx / WW;
    const int h = t % HH;
    const int b = t / HH;

    float v[27];
    #pragma unroll
    for (int i = 0; i < 3; ++i) {
        const int hh = h + i - 1;
        #pragma unroll
        for (int j = 0; j < 3; ++j) {
            const int ww = w + j - 1;
            const bool ok = (hh >= 0) && (hh < HH) && (ww >= 0) && (ww < WW);
            const float* p = x + (((long long)b * HH + hh) * WW + ww) * CC;
            #pragma unroll
            for (int c = 0; c < CC; ++c) {
                v[(i * 3 + j) * 3 + c] = ok ? p[c] : 0.0f;   // TF SAME zero pad
            }
        }
    }

    // Partial selection sort: after this, v[13] = 14th smallest = median.
    #pragma unroll
    for (int k = 0; k <= 13; ++k) {
        #pragma unroll
        for (int j = k + 1; j < 27; ++j) {
            const float lo = fminf(v[k], v[j]);
            const float hi = fmaxf(v[k], v[j]);
            v[k] = lo;
            v[j] = hi;
        }
    }
    const float m = v[13];
    med[idx] = m;

    // deterministic block-sum for the global mean
    __shared__ float sdata[256];
    sdata[threadIdx.x] = m;
    __syncthreads();
    #pragma unroll
    for (int s = 128; s > 0; s >>= 1) {
        if (threadIdx.x < s) sdata[threadIdx.x] += sdata[threadIdx.x + s];
        __syncthreads();
    }
    if (threadIdx.x == 0) partial[blockIdx.x] = sdata[0];
}

// ---------------- Kernel 2: reduce partials -> mean scalar ------------------
__global__ __launch_bounds__(256) void mean_kernel(const float* __restrict__ partial,
                                                   float* __restrict__ mean_out) {
    float s = 0.0f;
    for (int i = threadIdx.x; i < NBLK_MED; i += 256) s += partial[i];
    __shared__ float sdata[256];
    sdata[threadIdx.x] = s;
    __syncthreads();
    #pragma unroll
    for (int st = 128; st > 0; st >>= 1) {
        if (threadIdx.x < st) sdata[threadIdx.x] += sdata[threadIdx.x + st];
        __syncthreads();
    }
    if (threadIdx.x == 0) mean_out[0] = sdata[0] / (float)NPIX;
}

// ---------------- Kernel 2.5: center + zero-pad into [32][226][228] --------
__global__ __launch_bounds__(256) void center_pad_kernel(const float* __restrict__ med,
                                                         const float* __restrict__ mean_p,
                                                         float* __restrict__ cmed) {
    const int idx = blockIdx.x * 256 + threadIdx.x;   // < NPAD by construction
    const int b  = idx / PB;
    const int r  = idx % PB;
    const int hp = r / PW;
    const int wp = r % PW;
    float v = 0.0f;
    if (hp >= 1 && hp <= HH && wp >= 1 && wp <= WW) {
        v = med[((long long)b * HH + (hp - 1)) * WW + (wp - 1)] - mean_p[0];
    }
    cmed[idx] = v;   // written EVERY call (ws is not re-poisoned; stay deterministic)
}

// ---------------- Kernel 3: 3x3 conv, register-tiled ------------------------
// Block: one image row-tile of 32 pixels x 64 filters (2048 outputs).
// Thread: 8 pixels x 1 filter. f = tid&63 -> wave-uniform cmed loads
// (hardware broadcast), contiguous 256B stores per k.
__global__ __launch_bounds__(256) void conv_kernel(const float* __restrict__ cmed,
                                                   const float* __restrict__ Wt,
                                                   float* __restrict__ out) {
    const int bid = blockIdx.x;                 // 32*224*7 blocks
    const int wt = bid % 7;
    const int h  = (bid / 7) % HH;
    const int b  = bid / (7 * HH);

    const int f  = threadIdx.x & 63;
    const int g  = threadIdx.x >> 6;            // wave index 0..3
    const int pw = wt * 32 + g * 8;             // pixel start; mult of 8 -> 16B aligned

    float wreg[9];
    #pragma unroll
    for (int t = 0; t < 9; ++t) wreg[t] = Wt[t * FF + f];   // coalesced, cached

    float acc[8] = {0.f, 0.f, 0.f, 0.f, 0.f, 0.f, 0.f, 0.f};

    const float* base = cmed + (long long)b * PB + (long long)h * PW + pw;
    #pragma unroll
    for (int r = 0; r < 3; ++r) {
        const float4* row = (const float4*)(base + r * PW);
        const float4 a0 = row[0];
        const float4 a1 = row[1];
        const float4 a2 = row[2];               // cols pw..pw+11 (need pw..pw+9)
        const float cm[12] = {a0.x, a0.y, a0.z, a0.w,
                              a1.x, a1.y, a1.z, a1.w,
                              a2.x, a2.y, a2.z, a2.w};
        const float w0 = wreg[r * 3 + 0];
        const float w1 = wreg[r * 3 + 1];
        const float w2 = wreg[r * 3 + 2];
        #pragma unroll
        for (int k = 0; k < 8; ++k) {
            acc[k] = fmaf(cm[k], w0, acc[k]);
            acc[k] = fmaf(cm[k + 1], w1, acc[k]);
            acc[k] = fmaf(cm[k + 2], w2, acc[k]);
        }
    }

    float* op = out + (((long long)b * HH + h) * WW + pw) * FF + f;
    #pragma unroll
    for (int k = 0; k < 8; ++k) op[(long long)k * FF] = acc[k];
}

extern "C" void kernel_launch(void* const* d_in, const int* in_sizes, int n_in,
                              void* d_out, int out_size, void* d_ws, size_t ws_size,
                              hipStream_t stream) {
    const float* x  = (const float*)d_in[0];   // [32,224,224,3]
    const float* Wt = (const float*)d_in[1];   // [3,3,1,64]
    float* out = (float*)d_out;                // [32,224,224,64]

    // ws layout: cmed first (keeps its 16B alignment), then med, partials, mean
    float* cmed    = (float*)d_ws;             // NPAD floats (~6.6 MB)
    float* med     = cmed + NPAD;              // NPIX floats (~6.4 MB)
    float* partial = med + NPIX;               // NBLK_MED floats
    float* mean_p  = partial + NBLK_MED;       // 1 float

    median_kernel<<<NBLK_MED, 256, 0, stream>>>(x, med, partial);
    mean_kernel<<<1, 256, 0, stream>>>(partial, mean_p);
    center_pad_kernel<<<NPAD / 256, 256, 0, stream>>>(med, mean_p, cmed);

    const int nblk_conv = BB * HH * 7;         // 50,176
    conv_kernel<<<nblk_conv, 256, 0, stream>>>(cmed, Wt, out);
}

// Round 4
// 132.708 us; speedup vs baseline: 3.8022x; 1.0918x over previous
//
#include <hip/hip_runtime.h>

#define BB 32
#define HH 224
#define WW 224
#define CC 3
#define FF 64
#define NPIX (BB * HH * WW)          // 1,605,632
#define NOUT ((long long)NPIX * FF)  // 102,760,448

// padded median buffer: [32][226][228], zero borders
#define PH 226
#define PW 228
#define PB (PH * PW)                 // 51,528
#define NPAD (BB * PB)               // 1,648,896
#define NBLK_MED (NPAD / 256)        // 6441 exactly

// clang vector types (usable with __builtin_nontemporal_store)
typedef float f32x4 __attribute__((ext_vector_type(4)));
typedef float f32x4u __attribute__((ext_vector_type(4), aligned(4)));  // dword-aligned loads

// ---- Kernel 1: median of 27 -> padded buffer (borders 0) + partial sums ----
__global__ __launch_bounds__(256) void median_pad_kernel(const float* __restrict__ x,
                                                         float* __restrict__ cmed,
                                                         float* __restrict__ partial) {
    const int idx = blockIdx.x * 256 + threadIdx.x;   // < NPAD exactly
    const int b  = idx / PB;
    const int r  = idx % PB;
    const int hp = r / PW;
    const int wp = r % PW;

    float m = 0.0f;
    if (hp >= 1 && hp <= HH && wp >= 1 && wp <= WW) {
        const int h = hp - 1;
        const int w = wp - 1;
        float v[27];
        #pragma unroll
        for (int i = 0; i < 3; ++i) {
            const int hh = h + i - 1;
            #pragma unroll
            for (int j = 0; j < 3; ++j) {
                const int ww = w + j - 1;
                const bool ok = (hh >= 0) && (hh < HH) && (ww >= 0) && (ww < WW);
                const float* p = x + (((long long)b * HH + hh) * WW + ww) * CC;
                #pragma unroll
                for (int c = 0; c < CC; ++c) {
                    v[(i * 3 + j) * 3 + c] = ok ? p[c] : 0.0f;   // TF SAME zero pad
                }
            }
        }
        // Partial selection sort; v[13] = 14th smallest = exact median (verified R1/R2)
        #pragma unroll
        for (int k = 0; k <= 13; ++k) {
            #pragma unroll
            for (int j = k + 1; j < 27; ++j) {
                const float lo = fminf(v[k], v[j]);
                const float hi = fmaxf(v[k], v[j]);
                v[k] = lo;
                v[j] = hi;
            }
        }
        m = v[13];
    }
    cmed[idx] = m;   // borders get 0 every call (ws not re-poisoned between replays)

    // deterministic block-sum (border threads contribute 0)
    __shared__ float sdata[256];
    sdata[threadIdx.x] = m;
    __syncthreads();
    #pragma unroll
    for (int s = 128; s > 0; s >>= 1) {
        if (threadIdx.x < s) sdata[threadIdx.x] += sdata[threadIdx.x + s];
        __syncthreads();
    }
    if (threadIdx.x == 0) partial[blockIdx.x] = sdata[0];
}

// ---- Kernel 2: reduce partials -> mean; per-filter weight sums A[f] --------
__global__ __launch_bounds__(256) void mean_wsum_kernel(const float* __restrict__ partial,
                                                        const float* __restrict__ Wt,
                                                        float* __restrict__ mean_out,
                                                        float* __restrict__ Asum) {
    if (threadIdx.x < FF) {
        float s = 0.0f;
        #pragma unroll
        for (int t = 0; t < 9; ++t) s += Wt[t * FF + threadIdx.x];
        Asum[threadIdx.x] = s;
    }
    float s = 0.0f;
    for (int i = threadIdx.x; i < NBLK_MED; i += 256) s += partial[i];
    __shared__ float sdata[256];
    sdata[threadIdx.x] = s;
    __syncthreads();
    #pragma unroll
    for (int st = 128; st > 0; st >>= 1) {
        if (threadIdx.x < st) sdata[threadIdx.x] += sdata[threadIdx.x + st];
        __syncthreads();
    }
    if (threadIdx.x == 0) mean_out[0] = sdata[0] / (float)NPIX;
}

// ---- Kernel 3: 3x3 conv, 4 filters x 2 pixels / thread, x4 NT stores ------
// out[h][p][f] = sum_{in-bounds} (med - mean)*w = sum_9 med_pad*w  -  mean*S(h,p)
// S(h,p) = A - [h==0]*rowTop - [h==223]*rowBot - [p==0]*colL - [p==223]*colR
//            + corner add-backs (inclusion-exclusion).
__global__ __launch_bounds__(256) void conv_kernel(const float* __restrict__ cmed,
                                                   const float* __restrict__ Wt,
                                                   const float* __restrict__ Asum,
                                                   const float* __restrict__ mean_p,
                                                   float* __restrict__ out) {
    const int bid = blockIdx.x;                 // 32*224*7 = 50176
    const int wt = bid % 7;
    const int h  = (bid / 7) % HH;
    const int b  = bid / (7 * HH);

    const int fg = threadIdx.x & 15;            // filter group -> f4..f4+3
    const int pg = threadIdx.x >> 4;            // pixel group 0..15
    const int f4 = fg * 4;
    const int p  = wt * 32 + pg * 2;            // global col of pixel 0 (even)

    // 9 taps x 4 filters, dwordx4 loads (L2-broadcast)
    float w[9][4];
    #pragma unroll
    for (int t = 0; t < 9; ++t) {
        const f32x4u wv = *(const f32x4u*)(Wt + t * FF + f4);
        w[t][0] = wv.x; w[t][1] = wv.y; w[t][2] = wv.z; w[t][3] = wv.w;
    }
    const f32x4u Av = *(const f32x4u*)(Asum + f4);
    const float mean = mean_p[0];

    float acc0[4] = {0.f, 0.f, 0.f, 0.f};
    float acc1[4] = {0.f, 0.f, 0.f, 0.f};

    // padded rows h..h+2 = image rows h-1..h+1; padded cols p..p+3 cover both pixels
    const float* base = cmed + ((long long)b * PH + h) * PW + p;
    #pragma unroll
    for (int r = 0; r < 3; ++r) {
        const f32x4u cv = *(const f32x4u*)(base + (long long)r * PW);
        const float c0 = cv.x, c1 = cv.y, c2 = cv.z, c3 = cv.w;
        #pragma unroll
        for (int k = 0; k < 4; ++k) {
            acc0[k] = fmaf(c0, w[r * 3 + 0][k], acc0[k]);
            acc0[k] = fmaf(c1, w[r * 3 + 1][k], acc0[k]);
            acc0[k] = fmaf(c2, w[r * 3 + 2][k], acc0[k]);
            acc1[k] = fmaf(c1, w[r * 3 + 0][k], acc1[k]);
            acc1[k] = fmaf(c2, w[r * 3 + 1][k], acc1[k]);
            acc1[k] = fmaf(c3, w[r * 3 + 2][k], acc1[k]);
        }
    }

    // in-bounds weight sum per pixel
    float Sb[4] = {Av.x, Av.y, Av.z, Av.w};
    if (h == 0) {
        #pragma unroll
        for (int k = 0; k < 4; ++k) Sb[k] -= (w[0][k] + w[1][k] + w[2][k]);
    }
    if (h == HH - 1) {
        #pragma unroll
        for (int k = 0; k < 4; ++k) Sb[k] -= (w[6][k] + w[7][k] + w[8][k]);
    }
    float S0[4], S1[4];
    #pragma unroll
    for (int k = 0; k < 4; ++k) { S0[k] = Sb[k]; S1[k] = Sb[k]; }
    if (wt == 0 && pg == 0) {                   // pixel0 at col 0: left col invalid
        #pragma unroll
        for (int k = 0; k < 4; ++k) {
            S0[k] -= (w[0][k] + w[3][k] + w[6][k]);
            if (h == 0)      S0[k] += w[0][k];
            if (h == HH - 1) S0[k] += w[6][k];
        }
    }
    if (wt == 6 && pg == 15) {                  // pixel1 at col 223: right col invalid
        #pragma unroll
        for (int k = 0; k < 4; ++k) {
            S1[k] -= (w[2][k] + w[5][k] + w[8][k]);
            if (h == 0)      S1[k] += w[2][k];
            if (h == HH - 1) S1[k] += w[8][k];
        }
    }

    f32x4 o0, o1;
    o0.x = fmaf(-mean, S0[0], acc0[0]); o0.y = fmaf(-mean, S0[1], acc0[1]);
    o0.z = fmaf(-mean, S0[2], acc0[2]); o0.w = fmaf(-mean, S0[3], acc0[3]);
    o1.x = fmaf(-mean, S1[0], acc1[0]); o1.y = fmaf(-mean, S1[1], acc1[1]);
    o1.z = fmaf(-mean, S1[2], acc1[2]); o1.w = fmaf(-mean, S1[3], acc1[3]);

    float* op = out + (((long long)b * HH + h) * WW + p) * FF + f4;  // 16B aligned
    __builtin_nontemporal_store(o0, (f32x4*)op);
    __builtin_nontemporal_store(o1, (f32x4*)(op + FF));
}

extern "C" void kernel_launch(void* const* d_in, const int* in_sizes, int n_in,
                              void* d_out, int out_size, void* d_ws, size_t ws_size,
                              hipStream_t stream) {
    const float* x  = (const float*)d_in[0];   // [32,224,224,3]
    const float* Wt = (const float*)d_in[1];   // [3,3,1,64]
    float* out = (float*)d_out;                // [32,224,224,64]

    float* cmed    = (float*)d_ws;             // NPAD floats (~6.6 MB), 16B aligned
    float* Asum    = cmed + NPAD;              // 64 floats
    float* partial = Asum + FF;                // NBLK_MED floats
    float* mean_p  = partial + NBLK_MED;       // 1 float

    median_pad_kernel<<<NBLK_MED, 256, 0, stream>>>(x, cmed, partial);
    mean_wsum_kernel<<<1, 256, 0, stream>>>(partial, Wt, mean_p, Asum);

    const int nblk_conv = BB * HH * 7;         // 50,176
    conv_kernel<<<nblk_conv, 256, 0, stream>>>(cmed, Wt, Asum, mean_p, out);
}